// Round 7
// baseline (181.869 us; speedup 1.0000x reference)
//
#include <hip/hip_runtime.h>

// ---------------------------------------------------------------------------
// HIDecoder fused: y=z@Wy^T+by ; lin_{m,v}=einsum(gamma,W{m,v})+b ; gaussian
// log-lik epilogue.  gamma never materialized:
//   Weff[n=t*8+j][k] = sum_y M_j[t][y]*Wy[t*32+y][k],  M_j = Wm(j<4)/Wv(j>=4)
//   beff[n]          = b_j[t,d] + sum_y by[t*32+y]*M_j[t][y]
// => one (32768 x 512 x 256) bf16-MFMA GEMM + elementwise epilogue.
//
// R7: every prior round had grid == resident capacity (rounds=1, all blocks
// lockstep through phases -> no cross-phase overlap, the 53us plateau).
// Now: BM=32 x NH=128 (N-split 4), NT=256, grid 4096, LDS ~18KB ->
// 8 blocks/CU = 32 waves/CU (occupancy cap) and 2 dispatch rounds.
// weff L2 traffic 256MB (dense, fragment-ordered). VGPR<=64 via bounds(,8).
// ---------------------------------------------------------------------------

#define Bsz   32768
#define Tsz   64
#define Dsz   4
#define Ysz   32
#define Zsz   256
#define Nsz   512
#define BTtot (Bsz * Tsz)
#define EPS_  1e-3f
#define LOG2PI_ 1.8378770664093453f

#define BM       32            // batch rows per block
#define NH       128           // cols per block (quarter of Nsz) -> 16 t
#define NT       256           // threads per block (4 waves)
#define ASTRIDE  264           // ushorts per staged-z row (528 B)
#define LPAD     136           // ushorts per lin row (272 B, 16B-aligned)

typedef __attribute__((ext_vector_type(4))) float  f32x4;
typedef __attribute__((ext_vector_type(8))) short  short8;
typedef __attribute__((ext_vector_type(2))) unsigned int uint2v;

static __device__ __forceinline__ unsigned short f2bf(float f) {
    unsigned int u = __float_as_uint(f);
    return (unsigned short)((u + 0x7fffu + ((u >> 16) & 1u)) >> 16);   // RNE
}
static __device__ __forceinline__ float bf2f(unsigned short h) {
    return __uint_as_float(((unsigned int)h) << 16);
}

// ---------------------------------------------------------------------------
// Prep: 64 blocks (one per t) x 256 threads (one per k).
// weff B-fragment order: addr(n,k) = (tau*8+kk)*512 + (q*16+c)*8 + j,
//   tau=n>>4, c=n&15, kk=k>>5, q=(k>>3)&3, j=k&7.
// ---------------------------------------------------------------------------
__global__ __launch_bounds__(256)
void hidec_prep(const float* __restrict__ Wy, const float* __restrict__ by,
                const float* __restrict__ Wm, const float* __restrict__ bm,
                const float* __restrict__ Wv, const float* __restrict__ bv,
                unsigned short* __restrict__ weff, float* __restrict__ beff) {
    __shared__ float Ml[8][Ysz];
    __shared__ float byl[Ysz];
    const int t   = blockIdx.x;
    const int tid = threadIdx.x;
    {
        int j = tid >> 5, y = tid & 31;
        const float* src = (j < 4) ? Wm : Wv;
        Ml[j][y] = src[(t * Dsz + (j & 3)) * Ysz + y];
    }
    if (tid < Ysz) byl[tid] = by[t * Ysz + tid];
    __syncthreads();

    const int k = tid;
    const int kk = k >> 5, q = (k >> 3) & 3, je = k & 7;
    float wy[Ysz];
#pragma unroll
    for (int y = 0; y < Ysz; ++y)
        wy[y] = Wy[(size_t)(t * Ysz + y) * Zsz + k];
#pragma unroll
    for (int j = 0; j < 8; ++j) {
        float acc = 0.f;
#pragma unroll
        for (int y = 0; y < Ysz; ++y) acc = fmaf(Ml[j][y], wy[y], acc);
        int n   = t * 8 + j;
        int tau = n >> 4, c = n & 15;
        weff[((((tau * 8 + kk) * 4 + q) * 16 + c) * 8) + je] = f2bf(acc);
    }
    if (tid < 8) {
        int d = tid & 3;
        float s = ((tid < 4) ? bm : bv)[t * Dsz + d];
        for (int y = 0; y < Ysz; ++y) s = fmaf(byl[y], Ml[tid][y], s);
        beff[t * 8 + tid] = s;
    }
}

// ---------------------------------------------------------------------------
// Main: 4096 blocks x 256 threads (4 waves).
// block b: rows [(b>>2)*32, +32), N-quarter nq=b&3 (cols nq*128..+128,
// t in [nq*16,+16)). Wave w owns local taus w*2, w*2+1; 2 row-tiles of 16.
// ---------------------------------------------------------------------------
__global__ __launch_bounds__(NT, 8)
void hidec_main(const float* __restrict__ z, const float* __restrict__ bx,
                const int* __restrict__ miss, const float* __restrict__ dmean,
                const float* __restrict__ dvarp, const unsigned short* __restrict__ weff,
                const float* __restrict__ beff, float* __restrict__ out) {
    __shared__ unsigned short buf[BM * ASTRIDE];   // 16896 B; a_lds then lin (alias)
    __shared__ float4 sqA[16], dmA[16], dcA[16];
    __shared__ float  sldv[16];
    __shared__ float  beffL[NH];

    const int tid   = threadIdx.x;
    const int nq    = blockIdx.x & 3;
    const int nbase = nq * NH;
    const long row0 = (long)(blockIdx.x >> 2) * BM;

    // ---- per-(t,d) constants for this block's 16 t values -----------------
    if (tid < 16) {
        int t = nq * 16 + tid;
        float4 dv4 = *(const float4*)(dvarp + t * 4);
        float4 dm4 = *(const float4*)(dmean + t * 4);
        float d0 = fmaxf(dv4.x, EPS_), d1 = fmaxf(dv4.y, EPS_);
        float d2 = fmaxf(dv4.z, EPS_), d3 = fmaxf(dv4.w, EPS_);
        sqA[tid] = (float4){sqrtf(d0), sqrtf(d1), sqrtf(d2), sqrtf(d3)};
        dmA[tid] = dm4;
        dcA[tid] = (float4){d0, d1, d2, d3};
        sldv[tid] = __logf(d0) + __logf(d1) + __logf(d2) + __logf(d3);
    }
    if (tid < NH) beffL[tid] = beff[nbase + tid];

    // ---- stage z (32 x 256 fp32) -> bf16 LDS ------------------------------
    unsigned short* a_lds = buf;
#pragma unroll
    for (int i = 0; i < 8; ++i) {
        int idx4 = tid + i * NT;         // 2048 float4-groups
        int r  = idx4 >> 6;              // 0..31
        int c4 = idx4 & 63;
        float4 v = *(const float4*)(z + (row0 + r) * Zsz + c4 * 4);
        uint2v p;
        p.x = (unsigned)f2bf(v.x) | ((unsigned)f2bf(v.y) << 16);
        p.y = (unsigned)f2bf(v.z) | ((unsigned)f2bf(v.w) << 16);
        *(uint2v*)&a_lds[r * ASTRIDE + c4 * 4] = p;
    }
    __syncthreads();

    // ---- GEMM: 32 x 128 x K=256, bf16 MFMA 16x16x32 -----------------------
    const int lane = tid & 63;
    const int w    = tid >> 6;           // wave 0..3
    const int c    = lane & 15;
    const int q    = lane >> 4;

    f32x4 acc[4];                        // [tt*2 + rt]
#pragma unroll
    for (int i = 0; i < 4; ++i) acc[i] = (f32x4){0.f, 0.f, 0.f, 0.f};

    // wave taus: nq*8 + w*2 + {0,1}; per-tau block = 4096 ushorts
    const unsigned short* wp =
        weff + (size_t)(nq * 8 + w * 2) * 4096 + lane * 8;

#pragma unroll
    for (int kk = 0; kk < 8; ++kk) {
        short8 a0 = *(const short8*)&a_lds[(0 * 16 + c) * ASTRIDE + kk * 32 + q * 8];
        short8 a1 = *(const short8*)&a_lds[(1 * 16 + c) * ASTRIDE + kk * 32 + q * 8];
        short8 b0 = *(const short8*)(wp + (size_t)kk * 512);
        short8 b1 = *(const short8*)(wp + (size_t)kk * 512 + 4096);
        acc[0] = __builtin_amdgcn_mfma_f32_16x16x32_bf16(a0, b0, acc[0], 0, 0, 0);
        acc[1] = __builtin_amdgcn_mfma_f32_16x16x32_bf16(a1, b0, acc[1], 0, 0, 0);
        acc[2] = __builtin_amdgcn_mfma_f32_16x16x32_bf16(a0, b1, acc[2], 0, 0, 0);
        acc[3] = __builtin_amdgcn_mfma_f32_16x16x32_bf16(a1, b1, acc[3], 0, 0, 0);
    }
    __syncthreads();                     // all waves done reading a_lds

    // ---- write lin (bf16) into aliased buf --------------------------------
    // C layout: col = lane&15 (within tile), row(m) = quad*4 + reg
    unsigned short* lin = buf;
#pragma unroll
    for (int tt = 0; tt < 2; ++tt) {
        int n_loc = (w * 2 + tt) * 16 + c;           // 0..127
        float bb = beffL[n_loc];
#pragma unroll
        for (int rt = 0; rt < 2; ++rt) {
#pragma unroll
            for (int reg = 0; reg < 4; ++reg) {
                int rl = rt * 16 + q * 4 + reg;      // 0..31
                lin[rl * LPAD + n_loc] = f2bf(acc[tt * 2 + rt][reg] + bb);
            }
        }
    }
    __syncthreads();

    // ---- epilogue: 32 rows x 16 t = 512 tasks, 2 per thread ---------------
#pragma unroll
    for (int pp = 0; pp < 2; ++pp) {
        int task  = pp * NT + tid;
        int t_loc = task & 15;
        int rl    = task >> 4;           // 0..31
        int t     = nq * 16 + t_loc;
        long bt   = (row0 + rl) * Tsz + t;

        short8 l8 = *(const short8*)&lin[rl * LPAD + t_loc * 8];
        float lm[4], lv[4];
#pragma unroll
        for (int d = 0; d < 4; ++d) {
            lm[d] = bf2f((unsigned short)l8[d]);
            lv[d] = bf2f((unsigned short)l8[4 + d]);
        }

        float4 x4  = *(const float4*)(bx + bt * 4);
        float4 sq4 = sqA[t_loc];
        float4 dm4 = dmA[t_loc];
        float4 dc4 = dcA[t_loc];
        float xa[4]  = {x4.x,  x4.y,  x4.z,  x4.w};
        float sqa[4] = {sq4.x, sq4.y, sq4.z, sq4.w};
        float dma[4] = {dm4.x, dm4.y, dm4.z, dm4.w};
        float dca[4] = {dc4.x, dc4.y, dc4.z, dc4.w};

        float mean_o[4], var_o[4];
        float s = sldv[t_loc];
        float evp = 1.f;
#pragma unroll
        for (int d = 0; d < 4; ++d) {
            float mean = fmaf(sqa[d], lm[d], dma[d]);
            float v    = lv[d];
            float sp   = fmaxf(v, 0.f) + __logf(1.f + __expf(-fabsf(v)));
            float ev   = fminf(fmaxf(sp, EPS_), 1e20f);
            float var  = dca[d] * ev;
            float diff = xa[d] - mean;
            s = fmaf(diff * diff, __builtin_amdgcn_rcpf(var), s);
            evp *= ev;
            mean_o[d] = mean;
            var_o[d]  = var;
        }
        s += __logf(evp);
        float logp = -0.5f * (s + 4.f * LOG2PI_);
        float mk = (float)miss[bt];

        float lx = logp * mk;
        out[bt]         = lx;              // log_p_x
        out[BTtot + bt] = logp - lx;       // log_p_x_missing

        *(float4*)(out + 2L * BTtot + bt * 4) =
            (float4){mean_o[0], mean_o[1], mean_o[2], mean_o[3]};
        *(float4*)(out + 6L * BTtot + bt * 4) =
            (float4){var_o[0], var_o[1], var_o[2], var_o[3]};
    }
}

// ---------------------------------------------------------------------------
extern "C" void kernel_launch(void* const* d_in, const int* in_sizes, int n_in,
                              void* d_out, int out_size, void* d_ws, size_t ws_size,
                              hipStream_t stream) {
    const float* z     = (const float*)d_in[0];
    const float* bx    = (const float*)d_in[1];
    const int*   miss  = (const int*)d_in[2];
    const float* dmean = (const float*)d_in[3];
    const float* dvar  = (const float*)d_in[4];
    const float* Wy    = (const float*)d_in[5];
    const float* by    = (const float*)d_in[6];
    const float* Wm    = (const float*)d_in[7];
    const float* bm    = (const float*)d_in[8];
    const float* Wv    = (const float*)d_in[9];
    const float* bv    = (const float*)d_in[10];
    float* out = (float*)d_out;

    unsigned short* weff = (unsigned short*)d_ws;                    // 256 KiB
    float* beff = (float*)((char*)d_ws + 262144);                    // + 2 KiB

    hidec_prep<<<Tsz, Zsz, 0, stream>>>(Wy, by, Wm, bm, Wv, bv, weff, beff);
    hidec_main<<<(Bsz / BM) * 4, NT, 0, stream>>>(z, bx, miss, dmean, dvar, weff, beff, out);
}